// Round 1
// baseline (1877.377 us; speedup 1.0000x reference)
//
#include <hip/hip_runtime.h>

#define NB 50          // bins
#define DD 512         // feature dim
#define DCHUNK 128     // columns per block
#define ROWS_PER_BLOCK 2048
#define UNROLL 16
#define KSZ 5

// ---------------------------------------------------------------------------
// Pass 1: segment sum / sumsq / counts.
// grid = (DD/DCHUNK, N/ROWS_PER_BLOCK), block = 256.
// 256 threads = 2 row-groups x 128 columns; both groups share one LDS
// accumulator copy via ds_add_f32 (workgroup-scope fp atomic, no return).
// LDS: 25600B sum + 25600B sq + 8192B labels + 200B hist = 59592 B
//   -> 2 blocks/CU (8 waves/CU). [launch_bounds (256,2)]
// ---------------------------------------------------------------------------
__global__ __launch_bounds__(256, 2) void fds_reduce(
    const float* __restrict__ features,
    const int*   __restrict__ labels,
    float* __restrict__ g_sum,
    float* __restrict__ g_sq,
    float* __restrict__ g_cnt)
{
    __shared__ float s_sum[NB * DCHUNK];
    __shared__ float s_sq [NB * DCHUNK];
    __shared__ int   s_lab[ROWS_PER_BLOCK];
    __shared__ int   s_hist[NB];

    const int chunk = blockIdx.x;   // 0..3
    const int rblk  = blockIdx.y;
    const int tid   = threadIdx.x;

    for (int i = tid; i < NB * DCHUNK; i += 256) { s_sum[i] = 0.f; s_sq[i] = 0.f; }
    if (tid < NB) s_hist[tid] = 0;

    const int row0 = rblk * ROWS_PER_BLOCK;
    for (int i = tid; i < ROWS_PER_BLOCK; i += 256) s_lab[i] = labels[row0 + i];
    __syncthreads();

    // label histogram (only one D-chunk contributes, to count each row once)
    if (chunk == 0) {
        for (int i = tid; i < ROWS_PER_BLOCK; i += 256)
            __hip_atomic_fetch_add(&s_hist[s_lab[i]], 1,
                                   __ATOMIC_RELAXED, __HIP_MEMORY_SCOPE_WORKGROUP);
    }

    const int g = tid >> 7;             // row-group 0/1
    const int c = tid & (DCHUNK - 1);   // column within chunk
    const int rows_per_group = ROWS_PER_BLOCK / 2;  // 1024
    const int lrow0 = g * rows_per_group;
    const float* p = features + (size_t)(row0 + lrow0) * DD + chunk * DCHUNK + c;

    for (int it = 0; it < rows_per_group; it += UNROLL) {
        float v[UNROLL];
#pragma unroll
        for (int j = 0; j < UNROLL; ++j) v[j] = p[(size_t)(it + j) * DD];

        int lab[UNROLL];
        const int4* lp = (const int4*)&s_lab[lrow0 + it];   // 16B-aligned (it%16==0)
#pragma unroll
        for (int j = 0; j < UNROLL / 4; ++j) {
            int4 t = lp[j];
            lab[4*j+0] = t.x; lab[4*j+1] = t.y; lab[4*j+2] = t.z; lab[4*j+3] = t.w;
        }
#pragma unroll
        for (int j = 0; j < UNROLL; ++j) {
            const int o = lab[j] * DCHUNK + c;
            __hip_atomic_fetch_add(&s_sum[o], v[j],
                                   __ATOMIC_RELAXED, __HIP_MEMORY_SCOPE_WORKGROUP);
            __hip_atomic_fetch_add(&s_sq[o], v[j] * v[j],
                                   __ATOMIC_RELAXED, __HIP_MEMORY_SCOPE_WORKGROUP);
        }
    }
    __syncthreads();

    // flush block partials to global accumulators (agent-scope fp atomics)
    for (int b = g * (NB / 2); b < (g + 1) * (NB / 2); ++b) {
        const int go = b * DD + chunk * DCHUNK + c;
        const int lo = b * DCHUNK + c;
        __hip_atomic_fetch_add(&g_sum[go], s_sum[lo],
                               __ATOMIC_RELAXED, __HIP_MEMORY_SCOPE_AGENT);
        __hip_atomic_fetch_add(&g_sq[go], s_sq[lo],
                               __ATOMIC_RELAXED, __HIP_MEMORY_SCOPE_AGENT);
    }
    if (chunk == 0 && tid < NB)
        __hip_atomic_fetch_add(&g_cnt[tid], (float)s_hist[tid],
                               __ATOMIC_RELAXED, __HIP_MEMORY_SCOPE_AGENT);
}

// ---------------------------------------------------------------------------
// Pass 2: finalize. One thread per (bin, d). Recomputes blended mean/var for
// the 5-bin reflected smoothing window on the fly (stats are tiny, L2-hot).
// out layout: new_mean[25600] | new_var[25600] | new_num[50]
//             | smoothed_mean[25600] | smoothed_var[25600]
// ---------------------------------------------------------------------------
__global__ __launch_bounds__(256) void fds_finalize(
    const float* __restrict__ g_sum, const float* __restrict__ g_sq,
    const float* __restrict__ g_cnt,
    const float* __restrict__ running_mean, const float* __restrict__ running_var,
    const float* __restrict__ num_tracked, const float* __restrict__ kwin,
    float* __restrict__ out)
{
    __shared__ float s_cnt[NB];
    __shared__ float s_w[KSZ];
    const int tid = threadIdx.x;
    if (tid < NB)  s_cnt[tid] = g_cnt[tid];
    if (tid < KSZ) s_w[tid]   = kwin[tid];
    __syncthreads();

    const int idx = blockIdx.x * 256 + tid;   // 0..25599 (grid exactly 100)
    const int b = idx / DD;
    const int d = idx - b * DD;

    float sm = 0.f, sv = 0.f, my_nm = 0.f, my_nv = 0.f;
#pragma unroll
    for (int k = 0; k < KSZ; ++k) {
        const int i = b + k;
        // reflect-pad index into [0, NB)
        const int bb = (i < 2) ? (2 - i) : ((i >= NB + 2) ? (2 * NB - i) : (i - 2));
        const float cnt    = s_cnt[bb];
        const float safe_n = fmaxf(cnt, 1.f);
        const float s   = g_sum[bb * DD + d];
        const float sq  = g_sq [bb * DD + d];
        const float mean = s / safe_n;
        const float var  = (sq - safe_n * mean * mean) / fmaxf(cnt - 1.f, 1.f);
        const float rm = running_mean[bb * DD + d];
        const float rv = running_var [bb * DD + d];
        float nm, nv;
        if (cnt > 0.f) {
            nm = 0.1f * mean + 0.9f * rm;   // (1-f) rounds to 0.1f in fp32
            nv = 0.1f * var  + 0.9f * rv;
        } else {
            nm = rm; nv = rv;
        }
        sm += s_w[k] * nm;
        sv += s_w[k] * nv;
        if (k == 2) { my_nm = nm; my_nv = nv; }   // b+2 always maps to bin b
    }
    out[idx]                    = my_nm;                 // new_mean
    out[NB * DD + idx]          = my_nv;                 // new_var
    out[2 * NB * DD + NB + idx] = sm;                    // smoothed_mean
    out[3 * NB * DD + NB + idx] = sv;                    // smoothed_var
    if (idx < NB)
        out[2 * NB * DD + idx] = num_tracked[idx] + s_cnt[idx];   // new_num
}

extern "C" void kernel_launch(void* const* d_in, const int* in_sizes, int n_in,
                              void* d_out, int out_size, void* d_ws, size_t ws_size,
                              hipStream_t stream)
{
    const float* features     = (const float*)d_in[0];
    const int*   labels       = (const int*)  d_in[1];
    const float* running_mean = (const float*)d_in[2];
    const float* running_var  = (const float*)d_in[3];
    const float* num_tracked  = (const float*)d_in[4];
    const float* kwin         = (const float*)d_in[5];
    float* out = (float*)d_out;

    const int N = in_sizes[1];   // 262144 rows

    float* g_sum = (float*)d_ws;          // [NB*DD]
    float* g_sq  = g_sum + NB * DD;       // [NB*DD]
    float* g_cnt = g_sq  + NB * DD;       // [NB]
    hipMemsetAsync(d_ws, 0, (size_t)(2 * NB * DD + NB) * sizeof(float), stream);

    dim3 grid(DD / DCHUNK, N / ROWS_PER_BLOCK);   // (4, 128)
    fds_reduce<<<grid, 256, 0, stream>>>(features, labels, g_sum, g_sq, g_cnt);

    fds_finalize<<<NB * DD / 256, 256, 0, stream>>>(
        g_sum, g_sq, g_cnt, running_mean, running_var, num_tracked, kwin, out);
}

// Round 2
// 707.913 us; speedup vs baseline: 2.6520x; 2.6520x over previous
//
#include <hip/hip_runtime.h>

#define NB 50          // bins
#define DD 512         // feature dim
#define KSZ 5
#define SORT_ROWS 4096     // rows per sort block
#define EPT 16             // elements per thread in sort (4096/256)
#define RPW 512            // rows per wave in reduce
#define COLG 8             // column groups of 64 lanes (8*64 = 512 = DD)
#define UNR 8              // reduce inner unroll

// ---------------------------------------------------------------------------
// Pass 0: block-local counting sort of labels. Each block owns 4096 rows and
// writes packed (row<<6)|lab entries, grouped by bin, into its own segment of
// `packed`. Only 16 LDS atomics per thread (vs 2048 in round 1).
// Also accumulates the global per-bin counts.
// ---------------------------------------------------------------------------
__global__ __launch_bounds__(256) void fds_sort(
    const int* __restrict__ labels,
    int*       __restrict__ packed,   // [N]
    float*     __restrict__ g_cnt)    // [NB]
{
    __shared__ int s_hist[NB];
    __shared__ int s_cur[NB];
    const int tid  = threadIdx.x;
    const int base = blockIdx.x * SORT_ROWS;

    if (tid < NB) s_hist[tid] = 0;
    __syncthreads();

    int lab[EPT];
#pragma unroll
    for (int j = 0; j < EPT; ++j) {
        lab[j] = labels[base + j * 256 + tid];          // coalesced
        __hip_atomic_fetch_add(&s_hist[lab[j]], 1,
                               __ATOMIC_RELAXED, __HIP_MEMORY_SCOPE_WORKGROUP);
    }
    __syncthreads();

    if (tid == 0) {
        int run = 0;
        for (int b = 0; b < NB; ++b) { s_cur[b] = run; run += s_hist[b]; }
    }
    __syncthreads();

    if (tid < NB)
        __hip_atomic_fetch_add(&g_cnt[tid], (float)s_hist[tid],
                               __ATOMIC_RELAXED, __HIP_MEMORY_SCOPE_AGENT);

#pragma unroll
    for (int j = 0; j < EPT; ++j) {
        const int l   = lab[j];
        const int pos = __hip_atomic_fetch_add(&s_cur[l], 1,
                              __ATOMIC_RELAXED, __HIP_MEMORY_SCOPE_WORKGROUP);
        const int row = base + j * 256 + tid;
        packed[base + pos] = (row << 6) | l;
    }
}

// ---------------------------------------------------------------------------
// Pass 1: gather-reduce over bin-grouped rows. One wave = 64 consecutive
// columns x 512 sorted rows. Accumulator lives in 2 VGPRs; flush to global
// fp atomics only when the (wave-uniform) label changes (~7x per wave).
// No LDS in the hot loop.
// ---------------------------------------------------------------------------
__global__ __launch_bounds__(256) void fds_reduce(
    const float* __restrict__ features,
    const int*   __restrict__ packed,
    float* __restrict__ g_sum,
    float* __restrict__ g_sq)
{
    const int tid  = threadIdx.x;
    const int wave = tid >> 6;
    const int lane = tid & 63;
    const int gw   = blockIdx.x * 4 + wave;     // 0..4095
    const int cg     = gw & (COLG - 1);         // column group
    const int rchunk = gw >> 3;                 // 0..511
    const int col = cg * 64 + lane;
    const int r0  = rchunk * RPW;

    float sum = 0.f, sq = 0.f;
    int cur = packed[r0] & 63;                  // uniform across wave

    int pk[UNR];
#pragma unroll
    for (int j = 0; j < UNR; ++j) pk[j] = packed[r0 + j];   // broadcast loads

    for (int it = 0; it < RPW; it += UNR) {
        // feature loads for current batch
        float v[UNR];
#pragma unroll
        for (int j = 0; j < UNR; ++j)
            v[j] = features[(size_t)(pk[j] >> 6) * DD + col];

        // prefetch next batch of packed entries (breaks the dependent chain)
        int pk2[UNR];
        const int nb = (it + UNR < RPW) ? (r0 + it + UNR) : r0;
#pragma unroll
        for (int j = 0; j < UNR; ++j) pk2[j] = packed[nb + j];

#pragma unroll
        for (int j = 0; j < UNR; ++j) {
            const int l = pk[j] & 63;           // uniform
            if (l != cur) {                     // wave-coherent branch
                __hip_atomic_fetch_add(&g_sum[cur * DD + col], sum,
                                       __ATOMIC_RELAXED, __HIP_MEMORY_SCOPE_AGENT);
                __hip_atomic_fetch_add(&g_sq [cur * DD + col], sq,
                                       __ATOMIC_RELAXED, __HIP_MEMORY_SCOPE_AGENT);
                sum = 0.f; sq = 0.f; cur = l;
            }
            sum += v[j];
            sq = fmaf(v[j], v[j], sq);
        }
#pragma unroll
        for (int j = 0; j < UNR; ++j) pk[j] = pk2[j];
    }
    __hip_atomic_fetch_add(&g_sum[cur * DD + col], sum,
                           __ATOMIC_RELAXED, __HIP_MEMORY_SCOPE_AGENT);
    __hip_atomic_fetch_add(&g_sq [cur * DD + col], sq,
                           __ATOMIC_RELAXED, __HIP_MEMORY_SCOPE_AGENT);
}

// ---------------------------------------------------------------------------
// Pass 2: finalize (unchanged from round 1 — verified correct).
// out layout: new_mean[25600] | new_var[25600] | new_num[50]
//             | smoothed_mean[25600] | smoothed_var[25600]
// ---------------------------------------------------------------------------
__global__ __launch_bounds__(256) void fds_finalize(
    const float* __restrict__ g_sum, const float* __restrict__ g_sq,
    const float* __restrict__ g_cnt,
    const float* __restrict__ running_mean, const float* __restrict__ running_var,
    const float* __restrict__ num_tracked, const float* __restrict__ kwin,
    float* __restrict__ out)
{
    __shared__ float s_cnt[NB];
    __shared__ float s_w[KSZ];
    const int tid = threadIdx.x;
    if (tid < NB)  s_cnt[tid] = g_cnt[tid];
    if (tid < KSZ) s_w[tid]   = kwin[tid];
    __syncthreads();

    const int idx = blockIdx.x * 256 + tid;   // 0..25599 (grid exactly 100)
    const int b = idx / DD;
    const int d = idx - b * DD;

    float sm = 0.f, sv = 0.f, my_nm = 0.f, my_nv = 0.f;
#pragma unroll
    for (int k = 0; k < KSZ; ++k) {
        const int i = b + k;
        const int bb = (i < 2) ? (2 - i) : ((i >= NB + 2) ? (2 * NB - i) : (i - 2));
        const float cnt    = s_cnt[bb];
        const float safe_n = fmaxf(cnt, 1.f);
        const float s   = g_sum[bb * DD + d];
        const float sqv = g_sq [bb * DD + d];
        const float mean = s / safe_n;
        const float var  = (sqv - safe_n * mean * mean) / fmaxf(cnt - 1.f, 1.f);
        const float rm = running_mean[bb * DD + d];
        const float rv = running_var [bb * DD + d];
        float nm, nv;
        if (cnt > 0.f) {
            nm = 0.1f * mean + 0.9f * rm;
            nv = 0.1f * var  + 0.9f * rv;
        } else {
            nm = rm; nv = rv;
        }
        sm += s_w[k] * nm;
        sv += s_w[k] * nv;
        if (k == 2) { my_nm = nm; my_nv = nv; }
    }
    out[idx]                    = my_nm;
    out[NB * DD + idx]          = my_nv;
    out[2 * NB * DD + NB + idx] = sm;
    out[3 * NB * DD + NB + idx] = sv;
    if (idx < NB)
        out[2 * NB * DD + idx] = num_tracked[idx] + s_cnt[idx];
}

extern "C" void kernel_launch(void* const* d_in, const int* in_sizes, int n_in,
                              void* d_out, int out_size, void* d_ws, size_t ws_size,
                              hipStream_t stream)
{
    const float* features     = (const float*)d_in[0];
    const int*   labels       = (const int*)  d_in[1];
    const float* running_mean = (const float*)d_in[2];
    const float* running_var  = (const float*)d_in[3];
    const float* num_tracked  = (const float*)d_in[4];
    const float* kwin         = (const float*)d_in[5];
    float* out = (float*)d_out;

    const int N = in_sizes[1];   // 262144 rows

    // ws layout: g_sum[25600] | g_sq[25600] | g_cnt[50] | packed[N]
    float* g_sum  = (float*)d_ws;
    float* g_sq   = g_sum + NB * DD;
    float* g_cnt  = g_sq  + NB * DD;
    int*   packed = (int*)(g_cnt + NB);

    hipMemsetAsync(d_ws, 0, (size_t)(2 * NB * DD + NB) * sizeof(float), stream);

    fds_sort<<<N / SORT_ROWS, 256, 0, stream>>>(labels, packed, g_cnt);

    fds_reduce<<<(N / RPW) * COLG / 4, 256, 0, stream>>>(features, packed, g_sum, g_sq);

    fds_finalize<<<NB * DD / 256, 256, 0, stream>>>(
        g_sum, g_sq, g_cnt, running_mean, running_var, num_tracked, kwin, out);
}